// Round 1
// baseline (552.803 us; speedup 1.0000x reference)
//
#include <hip/hip_runtime.h>

#define NB 8192
#define ND 128
#define NC 1000

typedef __attribute__((ext_vector_type(8))) short bf16x8;
typedef __attribute__((ext_vector_type(4))) float f32x4;

__device__ __forceinline__ unsigned short f2bf(float f) {
    unsigned int u = __float_as_uint(f);
    return (unsigned short)((u + 0x7fffu + ((u >> 16) & 1u)) >> 16);
}

// ---------------- prep: fp32 -> bf16 copy of E, plus per-row squared norms ----------------
__global__ __launch_bounds__(64) void prep_kernel(const float* __restrict__ e,
                                                  unsigned short* __restrict__ ebf,
                                                  float* __restrict__ sq) {
    int r = blockIdx.x;
    int lane = threadIdx.x;
    const float* row = e + (size_t)r * ND;
    float2 v = *(const float2*)(row + lane * 2);
    unsigned int packed = (unsigned int)f2bf(v.x) | ((unsigned int)f2bf(v.y) << 16);
    *(unsigned int*)(ebf + (size_t)r * ND + lane * 2) = packed;
    float ss = v.x * v.x + v.y * v.y;
#pragma unroll
    for (int o = 32; o >= 1; o >>= 1) ss += __shfl_xor(ss, o);
    if (lane == 0) sq[r] = ss;
}

// ---------------- CE with label smoothing: one block per row ----------------
__global__ __launch_bounds__(256) void ce_kernel(const float* __restrict__ logits,
                                                 const int* __restrict__ labels,
                                                 float* __restrict__ acc) {
    __shared__ float row[NC];
    __shared__ float redm[4], reds[4], rede[4];
    int r = blockIdx.x, t = threadIdx.x;
    const float* x = logits + (size_t)r * NC;
    float m = -3.4e38f, s = 0.f;
    for (int k = t; k < NC; k += 256) {
        float v = x[k];
        row[k] = v;
        m = fmaxf(m, v);
        s += v;
    }
#pragma unroll
    for (int o = 32; o >= 1; o >>= 1) {
        m = fmaxf(m, __shfl_xor(m, o));
        s += __shfl_xor(s, o);
    }
    if ((t & 63) == 0) { redm[t >> 6] = m; reds[t >> 6] = s; }
    __syncthreads();
    m = fmaxf(fmaxf(redm[0], redm[1]), fmaxf(redm[2], redm[3]));
    float sumx = reds[0] + reds[1] + reds[2] + reds[3];
    float se = 0.f;
    for (int k = t; k < NC; k += 256) se += expf(row[k] - m);
#pragma unroll
    for (int o = 32; o >= 1; o >>= 1) se += __shfl_xor(se, o);
    if ((t & 63) == 0) rede[t >> 6] = se;
    __syncthreads();
    if (t == 0) {
        float lse = logf(rede[0] + rede[1] + rede[2] + rede[3]);
        float xl = row[labels[r]];
        float loss = (m + lse) - 0.9f * xl - 0.1f * (sumx * (1.0f / NC));
        atomicAdd(&acc[0], loss);
    }
}

// ---------------- mining: batch-hard triplet via bf16 MFMA, fp32 refine epilogue ----------------
// block = 256 threads = 4 waves; each wave owns 16 i-rows (A-frags in registers);
// sweeps all 8192 j-rows, B-frags read directly from L2-resident bf16 E.
__global__ __launch_bounds__(256) void mine_kernel(const float* __restrict__ e,
                                                   const unsigned short* __restrict__ ebf,
                                                   const float* __restrict__ sq,
                                                   const int* __restrict__ labels,
                                                   float* __restrict__ acc) {
    __shared__ int hpL[64], hnL[64], vaL[64];
    int tid = threadIdx.x;
    int wave = tid >> 6, lane = tid & 63;
    int col = lane & 15, grp = lane >> 4;
    int ib = blockIdx.x * 64 + wave * 16;

    // A fragments: A[row=col][k = c*32 + grp*8 .. +7], kept in registers for whole kernel
    bf16x8 afrag[4];
    const unsigned short* ap = ebf + (size_t)(ib + col) * ND + grp * 8;
#pragma unroll
    for (int c = 0; c < 4; ++c) afrag[c] = *(const bf16x8*)(ap + c * 32);

    // labels / norms for the 4 output rows this lane owns (C/D: row = grp*4 + r)
    int li[4];
    float sqi[4];
#pragma unroll
    for (int r = 0; r < 4; ++r) {
        li[r] = labels[ib + grp * 4 + r];
        sqi[r] = sq[ib + grp * 4 + r];
    }
    float bpv[4], bnv[4];
    int bpj[4], bnj[4];
#pragma unroll
    for (int r = 0; r < 4; ++r) {
        bpv[r] = -3.4e38f;
        bnv[r] = 3.4e38f;
        bpj[r] = 0;
        bnj[r] = 0;
    }

    for (int jt = 0; jt < NB / 16; ++jt) {
        int jb = jt * 16;
        const unsigned short* bp = ebf + (size_t)(jb + col) * ND + grp * 8;
        f32x4 c4 = {0.f, 0.f, 0.f, 0.f};
#pragma unroll
        for (int c = 0; c < 4; ++c) {
            bf16x8 bfrag = *(const bf16x8*)(bp + c * 32);
            c4 = __builtin_amdgcn_mfma_f32_16x16x32_bf16(afrag[c], bfrag, c4, 0, 0, 0);
        }
        int j = jb + col;
        int lj = labels[j];
        float sqj = sq[j];
#pragma unroll
        for (int r = 0; r < 4; ++r) {
            float d2 = sqi[r] + sqj - 2.0f * c4[r];
            int ig = ib + grp * 4 + r;
            if (lj == li[r]) {
                if (j != ig && d2 > bpv[r]) { bpv[r] = d2; bpj[r] = j; }
            } else {
                if (d2 < bnv[r]) { bnv[r] = d2; bnj[r] = j; }
            }
        }
        if ((jt & 7) == 7) __syncthreads();  // keep waves in lockstep for L1 reuse
    }

    // cross-lane argmax/argmin over the 16 columns (lanes sharing grp), tie -> smaller j
#pragma unroll
    for (int r = 0; r < 4; ++r) {
        float vp = bpv[r], vn = bnv[r];
        int jp = bpj[r], jn = bnj[r];
#pragma unroll
        for (int msk = 1; msk <= 8; msk <<= 1) {
            float ovp = __shfl_xor(vp, msk);
            int ojp = __shfl_xor(jp, msk);
            float ovn = __shfl_xor(vn, msk);
            int ojn = __shfl_xor(jn, msk);
            if (ovp > vp || (ovp == vp && ojp < jp)) { vp = ovp; jp = ojp; }
            if (ovn < vn || (ovn == vn && ojn < jn)) { vn = ovn; jn = ojn; }
        }
        if (col == 0) {
            int rowb = wave * 16 + grp * 4 + r;
            hpL[rowb] = jp;
            hnL[rowb] = jn;
            vaL[rowb] = (vp > -3.0e38f) && (vn < 3.0e38f);
        }
    }
    __syncthreads();

    // epilogue: exact fp32 distances with torch's +eps inside the norm, hinge, accumulate
    int rowb = tid >> 2, part = tid & 3;
    int ig = blockIdx.x * 64 + rowb;
    int hp = hpL[rowb], hn = hnL[rowb];
    int va = vaL[rowb];
    const float* a = e + (size_t)ig * ND + part * 32;
    const float* p = e + (size_t)hp * ND + part * 32;
    const float* n = e + (size_t)hn * ND + part * 32;
    float sap = 0.f, san = 0.f;
#pragma unroll
    for (int k = 0; k < 32; k += 4) {
        float4 av = *(const float4*)(a + k);
        float4 pv = *(const float4*)(p + k);
        float4 nv = *(const float4*)(n + k);
        float d;
        d = av.x - pv.x + 1e-6f; sap += d * d;
        d = av.y - pv.y + 1e-6f; sap += d * d;
        d = av.z - pv.z + 1e-6f; sap += d * d;
        d = av.w - pv.w + 1e-6f; sap += d * d;
        d = av.x - nv.x + 1e-6f; san += d * d;
        d = av.y - nv.y + 1e-6f; san += d * d;
        d = av.z - nv.z + 1e-6f; san += d * d;
        d = av.w - nv.w + 1e-6f; san += d * d;
    }
    sap += __shfl_xor(sap, 1);
    sap += __shfl_xor(sap, 2);
    san += __shfl_xor(san, 1);
    san += __shfl_xor(san, 2);
    if (part == 0 && va) {
        float per = fmaxf(sqrtf(sap) - sqrtf(san) + 0.5f, 0.0f);
        atomicAdd(&acc[1], per);
        atomicAdd(&acc[2], 1.0f);
    }
}

// ---------------- final combine ----------------
__global__ void fin_kernel(const float* __restrict__ acc, float* __restrict__ out) {
    float cls = acc[0] * (1.0f / NB);
    float tri = acc[2] > 0.5f ? acc[1] / acc[2] : 0.0f;
    out[0] = cls + tri;
}

extern "C" void kernel_launch(void* const* d_in, const int* in_sizes, int n_in,
                              void* d_out, int out_size, void* d_ws, size_t ws_size,
                              hipStream_t stream) {
    const float* logits = (const float*)d_in[0];
    const float* emb = (const float*)d_in[1];
    const int* labels = (const int*)d_in[2];

    float* acc = (float*)d_ws;                                      // [0]=cls_sum [1]=tri_sum [2]=cnt
    float* sq = (float*)((char*)d_ws + 256);                        // NB floats
    unsigned short* ebf = (unsigned short*)((char*)d_ws + 256 + NB * 4);  // NB*ND bf16

    hipMemsetAsync(d_ws, 0, 256, stream);
    prep_kernel<<<NB, 64, 0, stream>>>(emb, ebf, sq);
    ce_kernel<<<NB, 256, 0, stream>>>(logits, labels, acc);
    mine_kernel<<<NB / 64, 256, 0, stream>>>(emb, ebf, sq, labels, acc);
    fin_kernel<<<1, 1, 0, stream>>>(acc, (float*)d_out);
}

// Round 2
// 219.474 us; speedup vs baseline: 2.5188x; 2.5188x over previous
//
#include <hip/hip_runtime.h>

#define NB 8192
#define ND 128
#define NC 1000
#define NS 16          // j-slices
#define JS (NB / NS)   // 512 j per slice

typedef __attribute__((ext_vector_type(8))) short bf16x8;
typedef __attribute__((ext_vector_type(4))) float f32x4;

__device__ __forceinline__ unsigned short f2bf(float f) {
    unsigned int u = __float_as_uint(f);
    return (unsigned short)((u + 0x7fffu + ((u >> 16) & 1u)) >> 16);
}

// ---------------- prep: fp32 -> bf16 copy of E, plus per-row squared norms ----------------
// 4 waves/block, one row per wave
__global__ __launch_bounds__(256) void prep_kernel(const float* __restrict__ e,
                                                   unsigned short* __restrict__ ebf,
                                                   float* __restrict__ sq) {
    int wave = threadIdx.x >> 6, lane = threadIdx.x & 63;
    int r = blockIdx.x * 4 + wave;
    const float* row = e + (size_t)r * ND;
    float2 v = *(const float2*)(row + lane * 2);
    unsigned int packed = (unsigned int)f2bf(v.x) | ((unsigned int)f2bf(v.y) << 16);
    *(unsigned int*)(ebf + (size_t)r * ND + lane * 2) = packed;
    float ss = v.x * v.x + v.y * v.y;
#pragma unroll
    for (int o = 32; o >= 1; o >>= 1) ss += __shfl_xor(ss, o);
    if (lane == 0) sq[r] = ss;
}

// ---------------- CE with label smoothing: one wave per row, row in registers ----------------
__global__ __launch_bounds__(256) void ce_kernel(const float* __restrict__ logits,
                                                 const int* __restrict__ labels,
                                                 float* __restrict__ acc) {
    __shared__ float wsum[4];
    int wave = threadIdx.x >> 6, lane = threadIdx.x & 63;
    int gw = blockIdx.x * 4 + wave;
    float lsum = 0.f;
    for (int i = 0; i < 8; ++i) {
        int r = gw * 8 + i;
        const float* x = logits + (size_t)r * NC;
        // 250 float4 per row, row base is 16B-aligned (4000 B stride)
        float4 q0 = *(const float4*)(x + 4 * lane);
        float4 q1 = *(const float4*)(x + 256 + 4 * lane);
        float4 q2 = *(const float4*)(x + 512 + 4 * lane);
        float4 q3;
        bool a3 = (192 + lane) < 250;
        if (a3) q3 = *(const float4*)(x + 768 + 4 * lane);
        else q3 = make_float4(-3.4e38f, -3.4e38f, -3.4e38f, -3.4e38f);

        float m = fmaxf(fmaxf(fmaxf(q0.x, q0.y), fmaxf(q0.z, q0.w)),
                        fmaxf(fmaxf(q1.x, q1.y), fmaxf(q1.z, q1.w)));
        m = fmaxf(m, fmaxf(fmaxf(q2.x, q2.y), fmaxf(q2.z, q2.w)));
        m = fmaxf(m, fmaxf(fmaxf(q3.x, q3.y), fmaxf(q3.z, q3.w)));
        float s = (q0.x + q0.y + q0.z + q0.w) + (q1.x + q1.y + q1.z + q1.w) +
                  (q2.x + q2.y + q2.z + q2.w) +
                  (a3 ? (q3.x + q3.y + q3.z + q3.w) : 0.f);
#pragma unroll
        for (int o = 32; o >= 1; o >>= 1) {
            m = fmaxf(m, __shfl_xor(m, o));
            s += __shfl_xor(s, o);
        }
        // exp(-3.4e38 - m) underflows to 0, so inactive slots contribute nothing
        float se = expf(q0.x - m) + expf(q0.y - m) + expf(q0.z - m) + expf(q0.w - m) +
                   expf(q1.x - m) + expf(q1.y - m) + expf(q1.z - m) + expf(q1.w - m) +
                   expf(q2.x - m) + expf(q2.y - m) + expf(q2.z - m) + expf(q2.w - m) +
                   expf(q3.x - m) + expf(q3.y - m) + expf(q3.z - m) + expf(q3.w - m);
#pragma unroll
        for (int o = 32; o >= 1; o >>= 1) se += __shfl_xor(se, o);
        int lbl = labels[r];
        float xl = x[lbl];  // same address across lanes -> broadcast, row is L1-hot
        lsum += (m + logf(se)) - 0.9f * xl - 0.1f * (s * (1.0f / NC));
    }
    if (lane == 0) wsum[wave] = lsum;
    __syncthreads();
    if (threadIdx.x == 0)
        atomicAdd(&acc[0], wsum[0] + wsum[1] + wsum[2] + wsum[3]);
}

// ---------------- mining: batch-hard triplet via bf16 MFMA, j-sliced for occupancy ----------------
// grid (NB/64, NS); block = 4 waves; each wave owns 16 i-rows, sweeps JS j's of its slice.
__global__ __launch_bounds__(256) void mine_kernel(const unsigned short* __restrict__ ebf,
                                                   const float* __restrict__ sq,
                                                   const int* __restrict__ labels,
                                                   int4* __restrict__ part) {
    int tid = threadIdx.x;
    int wave = tid >> 6, lane = tid & 63;
    int col = lane & 15, grp = lane >> 4;
    int ib = blockIdx.x * 64 + wave * 16;
    int s = blockIdx.y;
    int jbase = s * JS;

    // A fragments: A[row=col][k = c*32 + grp*8 .. +7]
    bf16x8 afrag[4];
    const unsigned short* ap = ebf + (size_t)(ib + col) * ND + grp * 8;
#pragma unroll
    for (int c = 0; c < 4; ++c) afrag[c] = *(const bf16x8*)(ap + c * 32);

    int li[4];
    float sqi[4];
#pragma unroll
    for (int r = 0; r < 4; ++r) {
        li[r] = labels[ib + grp * 4 + r];
        sqi[r] = sq[ib + grp * 4 + r];
    }
    float bpv[4], bnv[4];
    int bpj[4], bnj[4];
#pragma unroll
    for (int r = 0; r < 4; ++r) {
        bpv[r] = -3.4e38f;
        bnv[r] = 3.4e38f;
        bpj[r] = 0;
        bnj[r] = 0;
    }

    for (int jt = 0; jt < JS / 16; ++jt) {
        int jb = jbase + jt * 16;
        const unsigned short* bp = ebf + (size_t)(jb + col) * ND + grp * 8;
        f32x4 c4 = {0.f, 0.f, 0.f, 0.f};
#pragma unroll
        for (int c = 0; c < 4; ++c) {
            bf16x8 bfrag = *(const bf16x8*)(bp + c * 32);
            c4 = __builtin_amdgcn_mfma_f32_16x16x32_bf16(afrag[c], bfrag, c4, 0, 0, 0);
        }
        int j = jb + col;
        int lj = labels[j];
        float sqj = sq[j];
#pragma unroll
        for (int r = 0; r < 4; ++r) {
            float d2 = sqi[r] + sqj - 2.0f * c4[r];
            int ig = ib + grp * 4 + r;
            if (lj == li[r]) {
                if (j != ig && d2 > bpv[r]) { bpv[r] = d2; bpj[r] = j; }
            } else {
                if (d2 < bnv[r]) { bnv[r] = d2; bnj[r] = j; }
            }
        }
    }

    // cross-lane argmax/argmin over the 16 columns (lanes sharing grp), tie -> smaller j
#pragma unroll
    for (int r = 0; r < 4; ++r) {
        float vp = bpv[r], vn = bnv[r];
        int jp = bpj[r], jn = bnj[r];
#pragma unroll
        for (int msk = 1; msk <= 8; msk <<= 1) {
            float ovp = __shfl_xor(vp, msk);
            int ojp = __shfl_xor(jp, msk);
            float ovn = __shfl_xor(vn, msk);
            int ojn = __shfl_xor(jn, msk);
            if (ovp > vp || (ovp == vp && ojp < jp)) { vp = ovp; jp = ojp; }
            if (ovn < vn || (ovn == vn && ojn < jn)) { vn = ovn; jn = ojn; }
        }
        if (col == 0) {
            int ig = ib + grp * 4 + r;
            part[((size_t)ig << 4) + s] =
                make_int4(__float_as_int(vp), jp, __float_as_int(vn), jn);
        }
    }
}

// ---------------- reduce: merge NS partials per row, fp32 hinge epilogue ----------------
// one wave per row, 4 waves/block
__global__ __launch_bounds__(256) void reduce_kernel(const float* __restrict__ e,
                                                     const int4* __restrict__ part,
                                                     float* __restrict__ acc) {
    __shared__ float wper[4], wcnt[4];
    int wave = threadIdx.x >> 6, lane = threadIdx.x & 63;
    int r = blockIdx.x * 4 + wave;

    // every 16-lane group reads the same 16 partials -> whole wave uniform after butterfly
    int4 q = part[((size_t)r << 4) + (lane & 15)];
    float vp = __int_as_float(q.x), vn = __int_as_float(q.z);
    int jp = q.y, jn = q.w;
#pragma unroll
    for (int msk = 1; msk <= 8; msk <<= 1) {
        float ovp = __shfl_xor(vp, msk);
        int ojp = __shfl_xor(jp, msk);
        float ovn = __shfl_xor(vn, msk);
        int ojn = __shfl_xor(jn, msk);
        if (ovp > vp || (ovp == vp && ojp < jp)) { vp = ovp; jp = ojp; }
        if (ovn < vn || (ovn == vn && ojn < jn)) { vn = ovn; jn = ojn; }
    }
    bool valid = (vp > -3.0e38f) && (vn < 3.0e38f);

    const float* a = e + (size_t)r * ND;
    const float* p = e + (size_t)jp * ND;
    const float* n = e + (size_t)jn * ND;
    float2 av = *(const float2*)(a + lane * 2);
    float2 pv = *(const float2*)(p + lane * 2);
    float2 nv = *(const float2*)(n + lane * 2);
    float d, sap = 0.f, san = 0.f;
    d = av.x - pv.x + 1e-6f; sap += d * d;
    d = av.y - pv.y + 1e-6f; sap += d * d;
    d = av.x - nv.x + 1e-6f; san += d * d;
    d = av.y - nv.y + 1e-6f; san += d * d;
#pragma unroll
    for (int o = 32; o >= 1; o >>= 1) {
        sap += __shfl_xor(sap, o);
        san += __shfl_xor(san, o);
    }
    if (lane == 0) {
        wper[wave] = valid ? fmaxf(sqrtf(sap) - sqrtf(san) + 0.5f, 0.0f) : 0.f;
        wcnt[wave] = valid ? 1.f : 0.f;
    }
    __syncthreads();
    if (threadIdx.x == 0) {
        atomicAdd(&acc[1], wper[0] + wper[1] + wper[2] + wper[3]);
        atomicAdd(&acc[2], wcnt[0] + wcnt[1] + wcnt[2] + wcnt[3]);
    }
}

// ---------------- final combine ----------------
__global__ void fin_kernel(const float* __restrict__ acc, float* __restrict__ out) {
    float cls = acc[0] * (1.0f / NB);
    float tri = acc[2] > 0.5f ? acc[1] / acc[2] : 0.0f;
    out[0] = cls + tri;
}

extern "C" void kernel_launch(void* const* d_in, const int* in_sizes, int n_in,
                              void* d_out, int out_size, void* d_ws, size_t ws_size,
                              hipStream_t stream) {
    const float* logits = (const float*)d_in[0];
    const float* emb = (const float*)d_in[1];
    const int* labels = (const int*)d_in[2];

    float* acc = (float*)d_ws;                                        // [0]=cls [1]=tri [2]=cnt
    float* sq = (float*)((char*)d_ws + 256);                          // NB floats
    unsigned short* ebf = (unsigned short*)((char*)d_ws + 256 + NB * 4);        // NB*ND bf16
    int4* part = (int4*)((char*)d_ws + 256 + NB * 4 + (size_t)NB * ND * 2);     // NB*NS int4

    hipMemsetAsync(d_ws, 0, 256, stream);
    prep_kernel<<<NB / 4, 256, 0, stream>>>(emb, ebf, sq);
    ce_kernel<<<NB / 32, 256, 0, stream>>>(logits, labels, acc);
    mine_kernel<<<dim3(NB / 64, NS), 256, 0, stream>>>(ebf, sq, labels, part);
    reduce_kernel<<<NB / 4, 256, 0, stream>>>(emb, part, acc);
    fin_kernel<<<1, 1, 0, stream>>>(acc, (float*)d_out);
}

// Round 3
// 141.724 us; speedup vs baseline: 3.9006x; 1.5486x over previous
//
#include <hip/hip_runtime.h>

#define NB 8192
#define ND 128
#define NC 1000
#define NS 16          // j-slices
#define JS (NB / NS)   // 512 j per slice
#define NT (JS / 16)   // 32 b-tiles per slice

typedef __attribute__((ext_vector_type(8))) short bf16x8;
typedef __attribute__((ext_vector_type(4))) float f32x4;

__device__ __forceinline__ unsigned short f2bf(float f) {
    unsigned int u = __float_as_uint(f);
    return (unsigned short)((u + 0x7fffu + ((u >> 16) & 1u)) >> 16);
}

// ---------------- prep: fp32 -> bf16 copy of E, plus per-row squared norms ----------------
__global__ __launch_bounds__(256) void prep_kernel(const float* __restrict__ e,
                                                   unsigned short* __restrict__ ebf,
                                                   float* __restrict__ sq) {
    int wave = threadIdx.x >> 6, lane = threadIdx.x & 63;
    int r = blockIdx.x * 4 + wave;
    const float* row = e + (size_t)r * ND;
    float2 v = *(const float2*)(row + lane * 2);
    unsigned int packed = (unsigned int)f2bf(v.x) | ((unsigned int)f2bf(v.y) << 16);
    *(unsigned int*)(ebf + (size_t)r * ND + lane * 2) = packed;
    float ss = v.x * v.x + v.y * v.y;
#pragma unroll
    for (int o = 32; o >= 1; o >>= 1) ss += __shfl_xor(ss, o);
    if (lane == 0) sq[r] = ss;
}

// ---------------- CE with label smoothing: ONE row per wave, 2048 blocks ----------------
__global__ __launch_bounds__(256) void ce_kernel(const float* __restrict__ logits,
                                                 const int* __restrict__ labels,
                                                 float* __restrict__ acc) {
    __shared__ float wsum[4];
    int wave = threadIdx.x >> 6, lane = threadIdx.x & 63;
    int r = blockIdx.x * 4 + wave;
    const float* x = logits + (size_t)r * NC;
    float4 q0 = *(const float4*)(x + 4 * lane);
    float4 q1 = *(const float4*)(x + 256 + 4 * lane);
    float4 q2 = *(const float4*)(x + 512 + 4 * lane);
    float4 q3;
    bool a3 = (192 + lane) < 250;
    if (a3) q3 = *(const float4*)(x + 768 + 4 * lane);
    else q3 = make_float4(-3.4e38f, -3.4e38f, -3.4e38f, -3.4e38f);

    float m = fmaxf(fmaxf(fmaxf(q0.x, q0.y), fmaxf(q0.z, q0.w)),
                    fmaxf(fmaxf(q1.x, q1.y), fmaxf(q1.z, q1.w)));
    m = fmaxf(m, fmaxf(fmaxf(q2.x, q2.y), fmaxf(q2.z, q2.w)));
    m = fmaxf(m, fmaxf(fmaxf(q3.x, q3.y), fmaxf(q3.z, q3.w)));
    float s = (q0.x + q0.y + q0.z + q0.w) + (q1.x + q1.y + q1.z + q1.w) +
              (q2.x + q2.y + q2.z + q2.w) +
              (a3 ? (q3.x + q3.y + q3.z + q3.w) : 0.f);
#pragma unroll
    for (int o = 32; o >= 1; o >>= 1) {
        m = fmaxf(m, __shfl_xor(m, o));
        s += __shfl_xor(s, o);
    }
    float se = expf(q0.x - m) + expf(q0.y - m) + expf(q0.z - m) + expf(q0.w - m) +
               expf(q1.x - m) + expf(q1.y - m) + expf(q1.z - m) + expf(q1.w - m) +
               expf(q2.x - m) + expf(q2.y - m) + expf(q2.z - m) + expf(q2.w - m) +
               expf(q3.x - m) + expf(q3.y - m) + expf(q3.z - m) + expf(q3.w - m);
#pragma unroll
    for (int o = 32; o >= 1; o >>= 1) se += __shfl_xor(se, o);
    float xl = x[labels[r]];
    float v = (m + logf(se)) - 0.9f * xl - 0.1f * (s * (1.0f / NC));
    if (lane == 0) wsum[wave] = v;
    __syncthreads();
    if (threadIdx.x == 0)
        atomicAdd(&acc[0], wsum[0] + wsum[1] + wsum[2] + wsum[3]);
}

// ---------------- mining: LDS-staged B-tiles (double-buffered), packed-key tracking ----------
// grid (NB/128, NS); block = 4 waves; wave owns 32 i-rows (2 A-tile register sets).
// B-tile (16 j-rows, 4KB) staged once per block via global_load_lds with XOR-swizzled source;
// ds_read_b128 applies the same swizzle -> ~conflict-free.
__global__ __launch_bounds__(256) void mine_kernel(const unsigned short* __restrict__ ebf,
                                                   const float* __restrict__ sq,
                                                   const int* __restrict__ labels,
                                                   uint2* __restrict__ part) {
    __shared__ unsigned short btile[2][16 * ND];  // 2 x 4KB
    __shared__ float pj_sq[JS];                   // sq[j] + 2.0
    __shared__ int pj_lb[JS];

    int tid = threadIdx.x;
    int wave = tid >> 6, lane = tid & 63;
    int col = lane & 15, grp = lane >> 4;
    int ib = blockIdx.x * 128 + wave * 32;
    int s = blockIdx.y, jbase = s * JS;

    // stage per-j labels/norms for the whole slice
    for (int k = tid; k < JS; k += 256) {
        pj_sq[k] = sq[jbase + k] + 2.0f;
        pj_lb[k] = labels[jbase + k];
    }

    // A fragments: 2 tiles x 4 k-chunks, kept in registers
    bf16x8 af0[4], af1[4];
    {
        const unsigned short* a0 = ebf + (size_t)(ib + col) * ND + (grp << 3);
        const unsigned short* a1 = ebf + (size_t)(ib + 16 + col) * ND + (grp << 3);
#pragma unroll
        for (int c = 0; c < 4; ++c) {
            af0[c] = *(const bf16x8*)(a0 + c * 32);
            af1[c] = *(const bf16x8*)(a1 + c * 32);
        }
    }
    int li[8];
#pragma unroll
    for (int a = 0; a < 2; ++a)
#pragma unroll
        for (int r = 0; r < 4; ++r) li[a * 4 + r] = labels[ib + a * 16 + grp * 4 + r];

    unsigned bp[8], bn[8];
#pragma unroll
    for (int k = 0; k < 8; ++k) { bp[k] = 0u; bn[k] = 0xFFFFFFFFu; }

    // stage: thread t fills LDS chunk t (row=t>>4, phys chunk p=t&15) with logical chunk p^(row&7)
#define STAGE(buf, jb)                                                               \
    do {                                                                             \
        const unsigned short* _src = ebf + (size_t)((jb) + (tid >> 4)) * ND +        \
                                     ((((tid & 15) ^ ((tid >> 4) & 7))) << 3);       \
        unsigned short* _dst = &btile[buf][0] + ((tid >> 6) << 9);                   \
        __builtin_amdgcn_global_load_lds(                                            \
            (const __attribute__((address_space(1))) unsigned int*)_src,             \
            (__attribute__((address_space(3))) unsigned int*)_dst, 16, 0, 0);        \
    } while (0)

    STAGE(0, jbase);
    __syncthreads();  // drains vmcnt+lgkmcnt: btile[0] and pj_* ready

    for (int jt = 0; jt < NT; ++jt) {
        int cur = jt & 1;
        if (jt + 1 < NT) STAGE(cur ^ 1, jbase + (jt + 1) * 16);

        int jl = (jt << 4) + col;
        float sqj2 = pj_sq[jl];
        int lj = pj_lb[jl];

        const unsigned short* bt = &btile[cur][0];
        bf16x8 bfr[4];
#pragma unroll
        for (int c = 0; c < 4; ++c) {
            int chunk = (grp + 4 * c) ^ (col & 7);
            bfr[c] = *(const bf16x8*)(bt + col * ND + chunk * 8);
        }

        f32x4 acc0 = {0.f, 0.f, 0.f, 0.f}, acc1 = {0.f, 0.f, 0.f, 0.f};
#pragma unroll
        for (int c = 0; c < 4; ++c) {
            acc0 = __builtin_amdgcn_mfma_f32_16x16x32_bf16(af0[c], bfr[c], acc0, 0, 0, 0);
            acc1 = __builtin_amdgcn_mfma_f32_16x16x32_bf16(af1[c], bfr[c], acc1, 0, 0, 0);
        }

        int jg = jbase + jl;
        unsigned jfp = 8191u - (unsigned)jg;
#pragma unroll
        for (int r = 0; r < 4; ++r) {
            float k0 = fmaf(-2.f, acc0[r], sqj2);
            unsigned b0 = ((__float_as_uint(k0) - 0x3F000000u) << 7) & 0xFFFFE000u;
            bool e0 = (lj == li[r]);
            bp[r] = max(bp[r], e0 ? (b0 | jfp) : 0u);
            bn[r] = min(bn[r], e0 ? 0xFFFFFFFFu : (b0 | (unsigned)jg));
            float k1 = fmaf(-2.f, acc1[r], sqj2);
            unsigned b1 = ((__float_as_uint(k1) - 0x3F000000u) << 7) & 0xFFFFE000u;
            bool e1 = (lj == li[4 + r]);
            bp[4 + r] = max(bp[4 + r], e1 ? (b1 | jfp) : 0u);
            bn[4 + r] = min(bn[4 + r], e1 ? 0xFFFFFFFFu : (b1 | (unsigned)jg));
        }
        __syncthreads();  // drains my STAGE (vmcnt) and protects buffer swap
    }

    // reduce over the 16 columns (within each 16-lane group), then store partials
#pragma unroll
    for (int k = 0; k < 8; ++k) {
#pragma unroll
        for (int msk = 1; msk <= 8; msk <<= 1) {
            bp[k] = max(bp[k], (unsigned)__shfl_xor((int)bp[k], msk));
            bn[k] = min(bn[k], (unsigned)__shfl_xor((int)bn[k], msk));
        }
    }
    if (col == 0) {
#pragma unroll
        for (int a = 0; a < 2; ++a)
#pragma unroll
            for (int r = 0; r < 4; ++r) {
                int gi = ib + a * 16 + grp * 4 + r;
                part[((size_t)gi << 4) + s] = make_uint2(bp[a * 4 + r], bn[a * 4 + r]);
            }
    }
}

// ---------------- reduce: merge NS packed partials per row, fp32 hinge epilogue ----------------
__global__ __launch_bounds__(256) void reduce_kernel(const float* __restrict__ e,
                                                     const uint2* __restrict__ part,
                                                     float* __restrict__ acc) {
    __shared__ float wper[4], wcnt[4];
    int wave = threadIdx.x >> 6, lane = threadIdx.x & 63;
    int r = blockIdx.x * 4 + wave;

    uint2 q = part[((size_t)r << 4) + (lane & 15)];
    unsigned bp = q.x, bn = q.y;
#pragma unroll
    for (int msk = 1; msk <= 8; msk <<= 1) {
        bp = max(bp, (unsigned)__shfl_xor((int)bp, msk));
        bn = min(bn, (unsigned)__shfl_xor((int)bn, msk));
    }
    int jp = 8191 - (int)(bp & 8191u);
    int jn = (int)(bn & 8191u);
    // self-index winning the pos-max means "no other same-class row" -> invalid
    bool valid = (bp != 0u) && (jp != r) && (bn != 0xFFFFFFFFu);

    const float* a = e + (size_t)r * ND;
    const float* p = e + (size_t)jp * ND;
    const float* n = e + (size_t)jn * ND;
    float2 av = *(const float2*)(a + lane * 2);
    float2 pv = *(const float2*)(p + lane * 2);
    float2 nv = *(const float2*)(n + lane * 2);
    float d, sap = 0.f, san = 0.f;
    d = av.x - pv.x + 1e-6f; sap += d * d;
    d = av.y - pv.y + 1e-6f; sap += d * d;
    d = av.x - nv.x + 1e-6f; san += d * d;
    d = av.y - nv.y + 1e-6f; san += d * d;
#pragma unroll
    for (int o = 32; o >= 1; o >>= 1) {
        sap += __shfl_xor(sap, o);
        san += __shfl_xor(san, o);
    }
    if (lane == 0) {
        wper[wave] = valid ? fmaxf(sqrtf(sap) - sqrtf(san) + 0.5f, 0.0f) : 0.f;
        wcnt[wave] = valid ? 1.f : 0.f;
    }
    __syncthreads();
    if (threadIdx.x == 0) {
        atomicAdd(&acc[1], wper[0] + wper[1] + wper[2] + wper[3]);
        atomicAdd(&acc[2], wcnt[0] + wcnt[1] + wcnt[2] + wcnt[3]);
    }
}

// ---------------- final combine ----------------
__global__ void fin_kernel(const float* __restrict__ acc, float* __restrict__ out) {
    float cls = acc[0] * (1.0f / NB);
    float tri = acc[2] > 0.5f ? acc[1] / acc[2] : 0.0f;
    out[0] = cls + tri;
}

extern "C" void kernel_launch(void* const* d_in, const int* in_sizes, int n_in,
                              void* d_out, int out_size, void* d_ws, size_t ws_size,
                              hipStream_t stream) {
    const float* logits = (const float*)d_in[0];
    const float* emb = (const float*)d_in[1];
    const int* labels = (const int*)d_in[2];

    float* acc = (float*)d_ws;                                            // [0]=cls [1]=tri [2]=cnt
    float* sq = (float*)((char*)d_ws + 256);                              // NB floats
    unsigned short* ebf = (unsigned short*)((char*)d_ws + 256 + NB * 4);  // NB*ND bf16
    uint2* part = (uint2*)((char*)d_ws + 256 + NB * 4 + (size_t)NB * ND * 2);  // NB*NS uint2

    hipMemsetAsync(d_ws, 0, 256, stream);
    prep_kernel<<<NB / 4, 256, 0, stream>>>(emb, ebf, sq);
    ce_kernel<<<NB / 4, 256, 0, stream>>>(logits, labels, acc);
    mine_kernel<<<dim3(NB / 128, NS), 256, 0, stream>>>(ebf, sq, labels, part);
    reduce_kernel<<<NB / 4, 256, 0, stream>>>(emb, part, acc);
    fin_kernel<<<1, 1, 0, stream>>>(acc, (float*)d_out);
}

// Round 4
// 64.657 us; speedup vs baseline: 8.5497x; 2.1919x over previous
//
#include <hip/hip_runtime.h>

#define NB 8192
#define ND 128
#define NC 1000
#define NS 32          // j-slices
#define JS (NB / NS)   // 256 j per slice
#define NT (JS / 16)   // 16 b-tiles per slice

typedef __attribute__((ext_vector_type(8))) short bf16x8;
typedef __attribute__((ext_vector_type(4))) float f32x4;

__device__ __forceinline__ unsigned short f2bf(float f) {
    unsigned int u = __float_as_uint(f);
    return (unsigned short)((u + 0x7fffu + ((u >> 16) & 1u)) >> 16);
}

// ---------------- prep: fp32 -> bf16 copy of E, plus per-row squared norms ----------------
__global__ __launch_bounds__(256) void prep_kernel(const float* __restrict__ e,
                                                   unsigned short* __restrict__ ebf,
                                                   float* __restrict__ sq) {
    int wave = threadIdx.x >> 6, lane = threadIdx.x & 63;
    int r = blockIdx.x * 4 + wave;
    const float* row = e + (size_t)r * ND;
    float2 v = *(const float2*)(row + lane * 2);
    unsigned int packed = (unsigned int)f2bf(v.x) | ((unsigned int)f2bf(v.y) << 16);
    *(unsigned int*)(ebf + (size_t)r * ND + lane * 2) = packed;
    float ss = v.x * v.x + v.y * v.y;
#pragma unroll
    for (int o = 32; o >= 1; o >>= 1) ss += __shfl_xor(ss, o);
    if (lane == 0) sq[r] = ss;
}

// ---------------- CE with label smoothing: one row per wave, partial per row (no atomics) ----
__global__ __launch_bounds__(256) void ce_kernel(const float* __restrict__ logits,
                                                 const int* __restrict__ labels,
                                                 float* __restrict__ cls_part) {
    int wave = threadIdx.x >> 6, lane = threadIdx.x & 63;
    int r = blockIdx.x * 4 + wave;
    const float* x = logits + (size_t)r * NC;
    float4 q0 = *(const float4*)(x + 4 * lane);
    float4 q1 = *(const float4*)(x + 256 + 4 * lane);
    float4 q2 = *(const float4*)(x + 512 + 4 * lane);
    float4 q3;
    bool a3 = (192 + lane) < 250;
    if (a3) q3 = *(const float4*)(x + 768 + 4 * lane);
    else q3 = make_float4(-3.4e38f, -3.4e38f, -3.4e38f, -3.4e38f);

    float m = fmaxf(fmaxf(fmaxf(q0.x, q0.y), fmaxf(q0.z, q0.w)),
                    fmaxf(fmaxf(q1.x, q1.y), fmaxf(q1.z, q1.w)));
    m = fmaxf(m, fmaxf(fmaxf(q2.x, q2.y), fmaxf(q2.z, q2.w)));
    m = fmaxf(m, fmaxf(fmaxf(q3.x, q3.y), fmaxf(q3.z, q3.w)));
    float s = (q0.x + q0.y + q0.z + q0.w) + (q1.x + q1.y + q1.z + q1.w) +
              (q2.x + q2.y + q2.z + q2.w) +
              (a3 ? (q3.x + q3.y + q3.z + q3.w) : 0.f);
#pragma unroll
    for (int o = 32; o >= 1; o >>= 1) {
        m = fmaxf(m, __shfl_xor(m, o));
        s += __shfl_xor(s, o);
    }
    float se = expf(q0.x - m) + expf(q0.y - m) + expf(q0.z - m) + expf(q0.w - m) +
               expf(q1.x - m) + expf(q1.y - m) + expf(q1.z - m) + expf(q1.w - m) +
               expf(q2.x - m) + expf(q2.y - m) + expf(q2.z - m) + expf(q2.w - m) +
               expf(q3.x - m) + expf(q3.y - m) + expf(q3.z - m) + expf(q3.w - m);
#pragma unroll
    for (int o = 32; o >= 1; o >>= 1) se += __shfl_xor(se, o);
    float xl = x[labels[r]];
    float v = (m + logf(se)) - 0.9f * xl - 0.1f * (s * (1.0f / NC));
    if (lane == 0) cls_part[r] = v;
}

// ---------------- mining: LDS-staged B-tiles (double-buffered), packed-key tracking ----------
// grid (NB/128, NS); block = 4 waves; wave owns 32 i-rows (2 A-tile register sets).
__global__ __launch_bounds__(256) void mine_kernel(const unsigned short* __restrict__ ebf,
                                                   const float* __restrict__ sq,
                                                   const int* __restrict__ labels,
                                                   uint2* __restrict__ part) {
    __shared__ unsigned short btile[2][16 * ND];  // 2 x 4KB
    __shared__ float pj_sq[JS];                   // sq[j] + 2.0
    __shared__ int pj_lb[JS];

    int tid = threadIdx.x;
    int wave = tid >> 6, lane = tid & 63;
    int col = lane & 15, grp = lane >> 4;
    int ib = blockIdx.x * 128 + wave * 32;
    int s = blockIdx.y, jbase = s * JS;

    // stage per-j labels/norms for the whole slice
    for (int k = tid; k < JS; k += 256) {
        pj_sq[k] = sq[jbase + k] + 2.0f;
        pj_lb[k] = labels[jbase + k];
    }

    // A fragments: 2 tiles x 4 k-chunks, kept in registers
    bf16x8 af0[4], af1[4];
    {
        const unsigned short* a0 = ebf + (size_t)(ib + col) * ND + (grp << 3);
        const unsigned short* a1 = ebf + (size_t)(ib + 16 + col) * ND + (grp << 3);
#pragma unroll
        for (int c = 0; c < 4; ++c) {
            af0[c] = *(const bf16x8*)(a0 + c * 32);
            af1[c] = *(const bf16x8*)(a1 + c * 32);
        }
    }
    int li[8];
#pragma unroll
    for (int a = 0; a < 2; ++a)
#pragma unroll
        for (int r = 0; r < 4; ++r) li[a * 4 + r] = labels[ib + a * 16 + grp * 4 + r];

    unsigned bp[8], bn[8];
#pragma unroll
    for (int k = 0; k < 8; ++k) { bp[k] = 0u; bn[k] = 0xFFFFFFFFu; }

    // stage: thread t fills LDS chunk t (row=t>>4, phys chunk p=t&15) with logical chunk p^(row&7)
#define STAGE(buf, jb)                                                               \
    do {                                                                             \
        const unsigned short* _src = ebf + (size_t)((jb) + (tid >> 4)) * ND +        \
                                     ((((tid & 15) ^ ((tid >> 4) & 7))) << 3);       \
        unsigned short* _dst = &btile[buf][0] + ((tid >> 6) << 9);                   \
        __builtin_amdgcn_global_load_lds(                                            \
            (const __attribute__((address_space(1))) unsigned int*)_src,             \
            (__attribute__((address_space(3))) unsigned int*)_dst, 16, 0, 0);        \
    } while (0)

    STAGE(0, jbase);
    __syncthreads();  // drains vmcnt+lgkmcnt: btile[0] and pj_* ready

    for (int jt = 0; jt < NT; ++jt) {
        int cur = jt & 1;
        if (jt + 1 < NT) STAGE(cur ^ 1, jbase + (jt + 1) * 16);

        int jl = (jt << 4) + col;
        float sqj2 = pj_sq[jl];
        int lj = pj_lb[jl];

        const unsigned short* bt = &btile[cur][0];
        bf16x8 bfr[4];
#pragma unroll
        for (int c = 0; c < 4; ++c) {
            int chunk = (grp + 4 * c) ^ (col & 7);
            bfr[c] = *(const bf16x8*)(bt + col * ND + chunk * 8);
        }

        f32x4 acc0 = {0.f, 0.f, 0.f, 0.f}, acc1 = {0.f, 0.f, 0.f, 0.f};
#pragma unroll
        for (int c = 0; c < 4; ++c) {
            acc0 = __builtin_amdgcn_mfma_f32_16x16x32_bf16(af0[c], bfr[c], acc0, 0, 0, 0);
            acc1 = __builtin_amdgcn_mfma_f32_16x16x32_bf16(af1[c], bfr[c], acc1, 0, 0, 0);
        }

        int jg = jbase + jl;
        unsigned jfp = 8191u - (unsigned)jg;
#pragma unroll
        for (int r = 0; r < 4; ++r) {
            float k0 = fmaf(-2.f, acc0[r], sqj2);
            unsigned b0 = ((__float_as_uint(k0) - 0x3F000000u) << 7) & 0xFFFFE000u;
            bool e0 = (lj == li[r]);
            bp[r] = max(bp[r], e0 ? (b0 | jfp) : 0u);
            bn[r] = min(bn[r], e0 ? 0xFFFFFFFFu : (b0 | (unsigned)jg));
            float k1 = fmaf(-2.f, acc1[r], sqj2);
            unsigned b1 = ((__float_as_uint(k1) - 0x3F000000u) << 7) & 0xFFFFE000u;
            bool e1 = (lj == li[4 + r]);
            bp[4 + r] = max(bp[4 + r], e1 ? (b1 | jfp) : 0u);
            bn[4 + r] = min(bn[4 + r], e1 ? 0xFFFFFFFFu : (b1 | (unsigned)jg));
        }
        __syncthreads();  // drains my STAGE (vmcnt) and protects buffer swap
    }

    // reduce over the 16 columns (within each 16-lane group), then store partials
#pragma unroll
    for (int k = 0; k < 8; ++k) {
#pragma unroll
        for (int msk = 1; msk <= 8; msk <<= 1) {
            bp[k] = max(bp[k], (unsigned)__shfl_xor((int)bp[k], msk));
            bn[k] = min(bn[k], (unsigned)__shfl_xor((int)bn[k], msk));
        }
    }
    if (col == 0) {
#pragma unroll
        for (int a = 0; a < 2; ++a)
#pragma unroll
            for (int r = 0; r < 4; ++r) {
                int gi = ib + a * 16 + grp * 4 + r;
                part[((size_t)gi << 5) + s] = make_uint2(bp[a * 4 + r], bn[a * 4 + r]);
            }
    }
}

// ---------------- reduce: merge NS packed partials per row, fp32 hinge, per-row partial -------
__global__ __launch_bounds__(256) void reduce_kernel(const float* __restrict__ e,
                                                     const uint2* __restrict__ part,
                                                     float2* __restrict__ tri_part) {
    int wave = threadIdx.x >> 6, lane = threadIdx.x & 63;
    int r = blockIdx.x * 4 + wave;

    // each 32-lane half reads the same 32 partials -> wave-uniform after butterfly
    uint2 q = part[((size_t)r << 5) + (lane & 31)];
    unsigned bp = q.x, bn = q.y;
#pragma unroll
    for (int msk = 1; msk <= 16; msk <<= 1) {
        bp = max(bp, (unsigned)__shfl_xor((int)bp, msk));
        bn = min(bn, (unsigned)__shfl_xor((int)bn, msk));
    }
    int jp = 8191 - (int)(bp & 8191u);
    int jn = (int)(bn & 8191u);
    // self winning the pos-max means "no other same-class row" -> invalid
    bool valid = (bp != 0u) && (jp != r) && (bn != 0xFFFFFFFFu);

    const float* a = e + (size_t)r * ND;
    const float* p = e + (size_t)jp * ND;
    const float* n = e + (size_t)jn * ND;
    float2 av = *(const float2*)(a + lane * 2);
    float2 pv = *(const float2*)(p + lane * 2);
    float2 nv = *(const float2*)(n + lane * 2);
    float d, sap = 0.f, san = 0.f;
    d = av.x - pv.x + 1e-6f; sap += d * d;
    d = av.y - pv.y + 1e-6f; sap += d * d;
    d = av.x - nv.x + 1e-6f; san += d * d;
    d = av.y - nv.y + 1e-6f; san += d * d;
#pragma unroll
    for (int o = 32; o >= 1; o >>= 1) {
        sap += __shfl_xor(sap, o);
        san += __shfl_xor(san, o);
    }
    if (lane == 0) {
        float per = valid ? fmaxf(sqrtf(sap) - sqrtf(san) + 0.5f, 0.0f) : 0.f;
        tri_part[r] = make_float2(per, valid ? 1.f : 0.f);
    }
}

// ---------------- final combine: single block tree-reduces all partials ----------------
__global__ __launch_bounds__(1024) void fin_kernel(const float* __restrict__ cls_part,
                                                   const float2* __restrict__ tri_part,
                                                   float* __restrict__ out) {
    __shared__ float sc[16], sp[16], sn[16];
    int t = threadIdx.x;
    int wave = t >> 6, lane = t & 63;
    float c = 0.f, tp = 0.f, tc = 0.f;
    for (int k = t; k < NB; k += 1024) {
        c += cls_part[k];
        float2 q = tri_part[k];
        tp += q.x;
        tc += q.y;
    }
#pragma unroll
    for (int o = 32; o >= 1; o >>= 1) {
        c += __shfl_xor(c, o);
        tp += __shfl_xor(tp, o);
        tc += __shfl_xor(tc, o);
    }
    if (lane == 0) { sc[wave] = c; sp[wave] = tp; sn[wave] = tc; }
    __syncthreads();
    if (t == 0) {
        float C = 0.f, P = 0.f, V = 0.f;
        for (int w = 0; w < 16; ++w) { C += sc[w]; P += sp[w]; V += sn[w]; }
        float cls = C * (1.0f / NB);
        float tri = V > 0.5f ? P / V : 0.0f;
        out[0] = cls + tri;
    }
}

extern "C" void kernel_launch(void* const* d_in, const int* in_sizes, int n_in,
                              void* d_out, int out_size, void* d_ws, size_t ws_size,
                              hipStream_t stream) {
    const float* logits = (const float*)d_in[0];
    const float* emb = (const float*)d_in[1];
    const int* labels = (const int*)d_in[2];

    char* w = (char*)d_ws;
    float* sq = (float*)w;                                   // NB f32        (32 KB)
    unsigned short* ebf = (unsigned short*)(w + NB * 4);     // NB*ND bf16    (2 MB)
    uint2* part = (uint2*)(w + NB * 4 + (size_t)NB * ND * 2);        // NB*NS uint2 (2 MB)
    float* cls_part = (float*)(w + NB * 4 + (size_t)NB * ND * 2 + (size_t)NB * NS * 8);  // NB f32
    float2* tri_part = (float2*)(w + NB * 4 + (size_t)NB * ND * 2 + (size_t)NB * NS * 8 + NB * 4);

    prep_kernel<<<NB / 4, 256, 0, stream>>>(emb, ebf, sq);
    ce_kernel<<<NB / 4, 256, 0, stream>>>(logits, labels, cls_part);
    mine_kernel<<<dim3(NB / 128, NS), 256, 0, stream>>>(ebf, sq, labels, part);
    reduce_kernel<<<NB / 4, 256, 0, stream>>>(emb, part, tri_part);
    fin_kernel<<<1, 1024, 0, stream>>>(cls_part, tri_part, (float*)d_out);
}

// Round 5
// 59.612 us; speedup vs baseline: 9.2734x; 1.0846x over previous
//
#include <hip/hip_runtime.h>

#define NB 8192
#define ND 128
#define NC 1000
#define NS 32          // j-slices
#define JS (NB / NS)   // 256 j per slice
#define NT (JS / 16)   // 16 b-tiles per slice

typedef __attribute__((ext_vector_type(8))) short bf16x8;
typedef __attribute__((ext_vector_type(4))) float f32x4;

__device__ __forceinline__ unsigned short f2bf(float f) {
    unsigned int u = __float_as_uint(f);
    return (unsigned short)((u + 0x7fffu + ((u >> 16) & 1u)) >> 16);
}

// ---------------- CE (label smoothing) fused with emb->bf16 conversion ----------------
// 2048 blocks x 4 waves; wave handles 1 logit row AND converts 1 emb row.
__global__ __launch_bounds__(256) void ce_prep_kernel(const float* __restrict__ logits,
                                                      const float* __restrict__ emb,
                                                      const int* __restrict__ labels,
                                                      unsigned short* __restrict__ ebf,
                                                      float* __restrict__ cls_part) {
    int wave = threadIdx.x >> 6, lane = threadIdx.x & 63;
    int r = blockIdx.x * 4 + wave;

    // emb row -> bf16 (rides under the logits-bound pass)
    {
        const float* erow = emb + (size_t)r * ND;
        float2 v = *(const float2*)(erow + lane * 2);
        unsigned int packed = (unsigned int)f2bf(v.x) | ((unsigned int)f2bf(v.y) << 16);
        *(unsigned int*)(ebf + (size_t)r * ND + lane * 2) = packed;
    }

    const float* x = logits + (size_t)r * NC;
    float4 q0 = *(const float4*)(x + 4 * lane);
    float4 q1 = *(const float4*)(x + 256 + 4 * lane);
    float4 q2 = *(const float4*)(x + 512 + 4 * lane);
    float4 q3;
    bool a3 = (192 + lane) < 250;
    if (a3) q3 = *(const float4*)(x + 768 + 4 * lane);
    else q3 = make_float4(-3.4e38f, -3.4e38f, -3.4e38f, -3.4e38f);

    float m = fmaxf(fmaxf(fmaxf(q0.x, q0.y), fmaxf(q0.z, q0.w)),
                    fmaxf(fmaxf(q1.x, q1.y), fmaxf(q1.z, q1.w)));
    m = fmaxf(m, fmaxf(fmaxf(q2.x, q2.y), fmaxf(q2.z, q2.w)));
    m = fmaxf(m, fmaxf(fmaxf(q3.x, q3.y), fmaxf(q3.z, q3.w)));
    float s = (q0.x + q0.y + q0.z + q0.w) + (q1.x + q1.y + q1.z + q1.w) +
              (q2.x + q2.y + q2.z + q2.w) +
              (a3 ? (q3.x + q3.y + q3.z + q3.w) : 0.f);
#pragma unroll
    for (int o = 32; o >= 1; o >>= 1) {
        m = fmaxf(m, __shfl_xor(m, o));
        s += __shfl_xor(s, o);
    }
    float se = expf(q0.x - m) + expf(q0.y - m) + expf(q0.z - m) + expf(q0.w - m) +
               expf(q1.x - m) + expf(q1.y - m) + expf(q1.z - m) + expf(q1.w - m) +
               expf(q2.x - m) + expf(q2.y - m) + expf(q2.z - m) + expf(q2.w - m) +
               expf(q3.x - m) + expf(q3.y - m) + expf(q3.z - m) + expf(q3.w - m);
#pragma unroll
    for (int o = 32; o >= 1; o >>= 1) se += __shfl_xor(se, o);
    float xl = x[labels[r]];
    float v = (m + logf(se)) - 0.9f * xl - 0.1f * (s * (1.0f / NC));
    if (lane == 0) cls_part[r] = v;
}

// ---------------- mining: depth-2 prefetch, counted vmcnt, dot-key tracking ----------------
// grid (NB/128, NS); 4 waves; wave owns 32 i-rows. Normalized embeddings:
// d2 ranking == (-dot) ranking, so key = monotone-packed(dot) | index.
// pos (farthest positive)  = MIN over same-class of key|j      (tie -> smaller j)
// neg (closest negative)   = MAX over diff-class of key|(8191-j) (tie -> smaller j)
__global__ __launch_bounds__(256) void mine_kernel(const unsigned short* __restrict__ ebf,
                                                   const int* __restrict__ labels,
                                                   uint2* __restrict__ part) {
    __shared__ unsigned short btile[3][16 * ND];  // 3 x 4KB
    __shared__ int pj_lb[JS];

    int tid = threadIdx.x;
    int wave = tid >> 6, lane = tid & 63;
    int col = lane & 15, grp = lane >> 4;
    int ib = blockIdx.x * 128 + wave * 32;
    int s = blockIdx.y, jbase = s * JS;

    for (int k = tid; k < JS; k += 256) pj_lb[k] = labels[jbase + k];

    // A fragments: 2 tiles x 4 k-chunks, registers for whole kernel
    bf16x8 af0[4], af1[4];
    {
        const unsigned short* a0 = ebf + (size_t)(ib + col) * ND + (grp << 3);
        const unsigned short* a1 = a0 + 16 * ND;
#pragma unroll
        for (int c = 0; c < 4; ++c) {
            af0[c] = *(const bf16x8*)(a0 + c * 32);
            af1[c] = *(const bf16x8*)(a1 + c * 32);
        }
    }
    int li[8];
#pragma unroll
    for (int a = 0; a < 2; ++a)
#pragma unroll
        for (int r = 0; r < 4; ++r) li[a * 4 + r] = labels[ib + a * 16 + grp * 4 + r];

    unsigned bp[8], bn[8];
#pragma unroll
    for (int k = 0; k < 8; ++k) { bp[k] = 0xFFFFFFFFu; bn[k] = 0u; }

    // thread t stages row (t>>4), phys chunk (t&15) <- logical chunk (t&15)^((t>>4)&7)
#define STAGE(buf, jb)                                                               \
    do {                                                                             \
        const unsigned short* _src = ebf + (size_t)((jb) + (tid >> 4)) * ND +        \
                                     ((((tid & 15) ^ ((tid >> 4) & 7))) << 3);       \
        unsigned short* _dst = &btile[buf][0] + ((tid >> 6) << 9);                   \
        __builtin_amdgcn_global_load_lds(                                            \
            (const __attribute__((address_space(1))) unsigned int*)_src,             \
            (__attribute__((address_space(3))) unsigned int*)_dst, 16, 0, 0);        \
    } while (0)

    STAGE(0, jbase);
    STAGE(1, jbase + 16);
    __syncthreads();  // prologue full drain: btile0/1 + pj_lb published

    for (int jt = 0; jt < NT; ++jt) {
        if (jt + 2 < NT) STAGE((jt + 2) % 3, jbase + (jt + 2) * 16);

        int jl = (jt << 4) + col;
        int lj = pj_lb[jl];
        int jg = jbase + jl;
        unsigned jfp = 8191u - (unsigned)jg;

        const unsigned short* bt = &btile[jt % 3][0];
        bf16x8 bfr[4];
#pragma unroll
        for (int c = 0; c < 4; ++c) {
            int chunk = (grp + 4 * c) ^ (col & 7);
            bfr[c] = *(const bf16x8*)(bt + col * ND + chunk * 8);
        }

        f32x4 acc0 = {0.f, 0.f, 0.f, 0.f}, acc1 = {0.f, 0.f, 0.f, 0.f};
#pragma unroll
        for (int c = 0; c < 4; ++c) {
            acc0 = __builtin_amdgcn_mfma_f32_16x16x32_bf16(af0[c], bfr[c], acc0, 0, 0, 0);
            acc1 = __builtin_amdgcn_mfma_f32_16x16x32_bf16(af1[c], bfr[c], acc1, 0, 0, 0);
        }

#pragma unroll
        for (int r = 0; r < 4; ++r) {
            unsigned k0 = ((__float_as_uint(acc0[r] + 2.0f) - 0x3F000000u) << 7) & 0xFFFFE000u;
            bool e0 = (lj == li[r]);
            bp[r] = min(bp[r], e0 ? (k0 | (unsigned)jg) : 0xFFFFFFFFu);
            bn[r] = max(bn[r], e0 ? 0u : (k0 | jfp));
            unsigned k1 = ((__float_as_uint(acc1[r] + 2.0f) - 0x3F000000u) << 7) & 0xFFFFE000u;
            bool e1 = (lj == li[4 + r]);
            bp[4 + r] = min(bp[4 + r], e1 ? (k1 | (unsigned)jg) : 0xFFFFFFFFu);
            bn[4 + r] = max(bn[4 + r], e1 ? 0u : (k1 | jfp));
        }

        // publish buf[jt+1]: my STAGE(jt+1) landed; leave STAGE(jt+2) in flight
        if (jt + 2 < NT) {
            asm volatile("s_waitcnt vmcnt(1)" ::: "memory");
            __builtin_amdgcn_sched_barrier(0);
            __builtin_amdgcn_s_barrier();
        } else if (jt + 1 < NT) {
            asm volatile("s_waitcnt vmcnt(0)" ::: "memory");
            __builtin_amdgcn_sched_barrier(0);
            __builtin_amdgcn_s_barrier();
        }
    }

    // reduce over the 16 columns (lanes sharing grp): pos=min, neg=max
#pragma unroll
    for (int k = 0; k < 8; ++k) {
#pragma unroll
        for (int msk = 1; msk <= 8; msk <<= 1) {
            bp[k] = min(bp[k], (unsigned)__shfl_xor((int)bp[k], msk));
            bn[k] = max(bn[k], (unsigned)__shfl_xor((int)bn[k], msk));
        }
    }
    if (col == 0) {
#pragma unroll
        for (int a = 0; a < 2; ++a)
#pragma unroll
            for (int r = 0; r < 4; ++r) {
                int gi = ib + a * 16 + grp * 4 + r;
                part[((size_t)gi << 5) + s] = make_uint2(bp[a * 4 + r], bn[a * 4 + r]);
            }
    }
}

// ---------------- reduce: merge NS packed partials per row, fp32 hinge, per-row partial -------
__global__ __launch_bounds__(256) void reduce_kernel(const float* __restrict__ e,
                                                     const uint2* __restrict__ part,
                                                     float2* __restrict__ tri_part) {
    int wave = threadIdx.x >> 6, lane = threadIdx.x & 63;
    int r = blockIdx.x * 4 + wave;

    uint2 q = part[((size_t)r << 5) + (lane & 31)];
    unsigned bp = q.x, bn = q.y;
#pragma unroll
    for (int msk = 1; msk <= 16; msk <<= 1) {
        bp = min(bp, (unsigned)__shfl_xor((int)bp, msk));
        bn = max(bn, (unsigned)__shfl_xor((int)bn, msk));
    }
    int jp = (int)(bp & 8191u);
    int jn = 8191 - (int)(bn & 8191u);
    // self winning pos-min means "no other same-class row" -> invalid
    bool valid = (bp != 0xFFFFFFFFu) && (jp != r) && (bn != 0u);

    const float* a = e + (size_t)r * ND;
    const float* p = e + (size_t)jp * ND;
    const float* n = e + (size_t)jn * ND;
    float2 av = *(const float2*)(a + lane * 2);
    float2 pv = *(const float2*)(p + lane * 2);
    float2 nv = *(const float2*)(n + lane * 2);
    float d, sap = 0.f, san = 0.f;
    d = av.x - pv.x + 1e-6f; sap += d * d;
    d = av.y - pv.y + 1e-6f; sap += d * d;
    d = av.x - nv.x + 1e-6f; san += d * d;
    d = av.y - nv.y + 1e-6f; san += d * d;
#pragma unroll
    for (int o = 32; o >= 1; o >>= 1) {
        sap += __shfl_xor(sap, o);
        san += __shfl_xor(san, o);
    }
    if (lane == 0) {
        float per = valid ? fmaxf(sqrtf(sap) - sqrtf(san) + 0.5f, 0.0f) : 0.f;
        tri_part[r] = make_float2(per, valid ? 1.f : 0.f);
    }
}

// ---------------- final combine: single block tree-reduces all partials ----------------
__global__ __launch_bounds__(1024) void fin_kernel(const float* __restrict__ cls_part,
                                                   const float2* __restrict__ tri_part,
                                                   float* __restrict__ out) {
    __shared__ float sc[16], sp[16], sn[16];
    int t = threadIdx.x;
    int wave = t >> 6, lane = t & 63;
    float c = 0.f, tp = 0.f, tc = 0.f;
    for (int k = t; k < NB; k += 1024) {
        c += cls_part[k];
        float2 q = tri_part[k];
        tp += q.x;
        tc += q.y;
    }
#pragma unroll
    for (int o = 32; o >= 1; o >>= 1) {
        c += __shfl_xor(c, o);
        tp += __shfl_xor(tp, o);
        tc += __shfl_xor(tc, o);
    }
    if (lane == 0) { sc[wave] = c; sp[wave] = tp; sn[wave] = tc; }
    __syncthreads();
    if (t == 0) {
        float C = 0.f, P = 0.f, V = 0.f;
        for (int w = 0; w < 16; ++w) { C += sc[w]; P += sp[w]; V += sn[w]; }
        float cls = C * (1.0f / NB);
        float tri = V > 0.5f ? P / V : 0.0f;
        out[0] = cls + tri;
    }
}

extern "C" void kernel_launch(void* const* d_in, const int* in_sizes, int n_in,
                              void* d_out, int out_size, void* d_ws, size_t ws_size,
                              hipStream_t stream) {
    const float* logits = (const float*)d_in[0];
    const float* emb = (const float*)d_in[1];
    const int* labels = (const int*)d_in[2];

    char* w = (char*)d_ws;
    unsigned short* ebf = (unsigned short*)w;                        // NB*ND bf16 (2 MB)
    uint2* part = (uint2*)(w + (size_t)NB * ND * 2);                 // NB*NS uint2 (2 MB)
    float* cls_part = (float*)(w + (size_t)NB * ND * 2 + (size_t)NB * NS * 8);  // NB f32
    float2* tri_part = (float2*)(w + (size_t)NB * ND * 2 + (size_t)NB * NS * 8 + NB * 4);

    ce_prep_kernel<<<NB / 4, 256, 0, stream>>>(logits, emb, labels, ebf, cls_part);
    mine_kernel<<<dim3(NB / 128, NS), 256, 0, stream>>>(ebf, labels, part);
    reduce_kernel<<<NB / 4, 256, 0, stream>>>(emb, part, tri_part);
    fin_kernel<<<1, 1024, 0, stream>>>(cls_part, tri_part, (float*)d_out);
}